// Round 9
// baseline (413.412 us; speedup 1.0000x reference)
//
#include <hip/hip_runtime.h>
#include <stdint.h>

#define DIM   512
#define CBSZ  8192
#define BN    8192
#define LDSS  132       // f32 GEMM pad (k_implicit, unchanged structure)

#define LOSC  4096.0f   // residual scale 2^12 (keeps f16 residuals normal)
#define LOSCI (1.0f/4096.0f)
#define BK    32        // k-tile (f16 elems); r9: back to 32 + double-buffer

typedef _Float16 f16x8 __attribute__((ext_vector_type(8)));
typedef _Float16 f16x4 __attribute__((ext_vector_type(4)));
typedef float    f32x4 __attribute__((ext_vector_type(4)));

// Monotone float->uint mapping: float order == unsigned order.
__device__ __forceinline__ unsigned int fkey(float v) {
  unsigned int u = __float_as_uint(v);
  return (u & 0x80000000u) ? ~u : (u | 0x80000000u);
}

// async global->LDS, 16 B per lane; LDS dest = wave-uniform base + lane*16
__device__ __forceinline__ void gload16(const void* g, void* l) {
  __builtin_amdgcn_global_load_lds(
      (const __attribute__((address_space(1))) void*)g,
      (__attribute__((address_space(3))) void*)l, 16, 0, 0);
}

// ---------------------------------------------------------------------------
// Split x (f32) into hi/lo f16 arrays (lo scaled by 2^12).
// ---------------------------------------------------------------------------
__global__ __launch_bounds__(256) void k_split(
    const float* __restrict__ in, _Float16* __restrict__ hi,
    _Float16* __restrict__ lo) {
  const int t = blockIdx.x * 256 + threadIdx.x;
  const float4* p = (const float4*)in + (size_t)t * 2;
  float4 v0 = p[0], v1 = p[1];
  float vv[8] = {v0.x, v0.y, v0.z, v0.w, v1.x, v1.y, v1.z, v1.w};
  f16x8 h, l;
#pragma unroll
  for (int j = 0; j < 8; ++j) {
    h[j] = (_Float16)vv[j];
    l[j] = (_Float16)((vv[j] - (float)h[j]) * LOSC);
  }
  *(f16x8*)(hi + (size_t)t * 8) = h;
  *(f16x8*)(lo + (size_t)t * 8) = l;
}

// ---------------------------------------------------------------------------
// Kernel A: implicit = codebook @ W^T (f32 vector GEMM, bit-matches XLA ref),
// epilogue also writes hi/lo f16 split of implicit + accumulates c2.
// ---------------------------------------------------------------------------
__global__ __launch_bounds__(256) void k_implicit(
    const float* __restrict__ cb, const float* __restrict__ Wm,
    float* __restrict__ imp, _Float16* __restrict__ imph,
    _Float16* __restrict__ impl, float* __restrict__ c2) {
  __shared__ float As[32][LDSS];
  __shared__ float Bs[32][LDSS];
  const int t  = threadIdx.x;
  const int tx = t & 15, ty = t >> 4;
  const int tm0 = blockIdx.x * 128;
  const int tn0 = blockIdx.y * 128;
  float acc[8][8];
#pragma unroll
  for (int i = 0; i < 8; ++i)
#pragma unroll
    for (int j = 0; j < 8; ++j) acc[i][j] = 0.f;

  const int chunk = t & 7, row0 = t >> 3;
  for (int kt = 0; kt < DIM; kt += 32) {
#pragma unroll
    for (int rr = 0; rr < 4; ++rr) {
      int row = row0 + rr * 32;
      float4 av = *(const float4*)(cb + (size_t)(tm0 + row) * DIM + kt + chunk * 4);
      float4 bv = *(const float4*)(Wm + (size_t)(tn0 + row) * DIM + kt + chunk * 4);
      As[chunk*4+0][row] = av.x; As[chunk*4+1][row] = av.y;
      As[chunk*4+2][row] = av.z; As[chunk*4+3][row] = av.w;
      Bs[chunk*4+0][row] = bv.x; Bs[chunk*4+1][row] = bv.y;
      Bs[chunk*4+2][row] = bv.z; Bs[chunk*4+3][row] = bv.w;
    }
    __syncthreads();
#pragma unroll
    for (int k = 0; k < 32; ++k) {
      float4 a0 = *(const float4*)&As[k][ty * 4];
      float4 a1 = *(const float4*)&As[k][64 + ty * 4];
      float4 b0 = *(const float4*)&Bs[k][tx * 4];
      float4 b1 = *(const float4*)&Bs[k][64 + tx * 4];
      float av[8] = {a0.x, a0.y, a0.z, a0.w, a1.x, a1.y, a1.z, a1.w};
      float bv[8] = {b0.x, b0.y, b0.z, b0.w, b1.x, b1.y, b1.z, b1.w};
#pragma unroll
      for (int i = 0; i < 8; ++i)
#pragma unroll
        for (int j = 0; j < 8; ++j) acc[i][j] = fmaf(av[i], bv[j], acc[i][j]);
    }
    __syncthreads();
  }
#pragma unroll
  for (int i = 0; i < 8; ++i) {
    int rl = ((i >> 2) << 6) + ty * 4 + (i & 3);
    int rg = tm0 + rl;
    float s = 0.f;
#pragma unroll
    for (int jh = 0; jh < 2; ++jh) {
      float4 v = make_float4(acc[i][jh*4+0], acc[i][jh*4+1], acc[i][jh*4+2], acc[i][jh*4+3]);
      int cg = tn0 + (jh << 6) + tx * 4;
      *(float4*)(imp + (size_t)rg * DIM + cg) = v;
      float vs[4] = {v.x, v.y, v.z, v.w};
      f16x4 vh, vl;
#pragma unroll
      for (int q = 0; q < 4; ++q) {
        vh[q] = (_Float16)vs[q];
        vl[q] = (_Float16)((vs[q] - (float)vh[q]) * LOSC);
      }
      *(f16x4*)(imph + (size_t)rg * DIM + cg) = vh;
      *(f16x4*)(impl + (size_t)rg * DIM + cg) = vl;
      s += v.x*v.x + v.y*v.y + v.z*v.z + v.w*v.w;
    }
    atomicAdd(&c2[rg], s);
  }
}

// ---------------------------------------------------------------------------
// Kernel B v5: fused x @ implicit^T + per-row argmin, f16-split 3-pass MFMA.
// 2-phase double-buffered pipeline (T3-minimum): issue next tile's
// global_load_lds BEFORE the MFMA cluster, drain vmcnt(0) AFTER it (load
// latency hides under ~48 MFMAs), ONE raw s_barrier per K-tile.
// LDS layout = r7-validated BK=32 XOR swizzle (row 128 B, 8 slots, physical
// slot = logical ^ (row&7)); inverse swizzle on global source address.
// Accumulation k-order unchanged -> bit-identical results.
// ---------------------------------------------------------------------------
__global__ __launch_bounds__(256, 2) void k_argmin(
    const _Float16* __restrict__ xh, const _Float16* __restrict__ xl,
    const _Float16* __restrict__ ch, const _Float16* __restrict__ cl,
    const float* __restrict__ c2, unsigned long long* __restrict__ best) {
  __shared__ _Float16 As[2][128 * 64];   // 16 KB x2
  __shared__ _Float16 Bs[2][128 * 64];   // 16 KB x2
  const int t    = threadIdx.x;
  const int lane = t & 63, w = t >> 6;
  const int wm = w >> 1, wn = w & 1;
  const int fr = lane & 15, fq = lane >> 4;
  const int tm0 = blockIdx.x * 128;   // x rows
  const int tn0 = blockIdx.y * 128;   // codebook entries

  f32x4 ahh[4][4], axx[4][4];
#pragma unroll
  for (int i = 0; i < 4; ++i)
#pragma unroll
    for (int j = 0; j < 4; ++j) {
      ahh[i][j] = (f32x4){0.f, 0.f, 0.f, 0.f};
      axx[i][j] = (f32x4){0.f, 0.f, 0.f, 0.f};
    }

  // staging: lane l -> row (l>>3), physical slot (l&7); logical slot
  // s = (l&7)^(l>>3); s&4 -> lo array, s&3 -> 16 B k-chunk.
  const int s_   = (lane & 7) ^ (lane >> 3);
  const int rofs = lane >> 3;
  const _Float16* baseA = (s_ & 4) ? xl : xh;
  const _Float16* baseB = (s_ & 4) ? cl : ch;
  const _Float16* gAq[4];
  const _Float16* gBq[4];
#pragma unroll
  for (int q = 0; q < 4; ++q) {
    int rA = tm0 + w * 32 + q * 8 + rofs;
    int rB = tn0 + w * 32 + q * 8 + rofs;
    gAq[q] = baseA + (size_t)rA * DIM + (s_ & 3) * 8;
    gBq[q] = baseB + (size_t)rB * DIM + (s_ & 3) * 8;
  }

  // fragment read byte offsets (k-invariant); lo fragment = hi ^ 64
  int rAoff[4], rBoff[4];
#pragma unroll
  for (int i = 0; i < 4; ++i) {
    rAoff[i] = (wm * 64 + i * 16 + fr) * 128 + ((fq ^ (fr & 7)) << 4);
    rBoff[i] = (wn * 64 + i * 16 + fr) * 128 + ((fq ^ (fr & 7)) << 4);
  }

  // prologue: stage tile 0 into buffer 0, drain, sync
#pragma unroll
  for (int q = 0; q < 4; ++q) {
    gload16(gAq[q], (char*)As[0] + (w * 32 + q * 8) * 128);
    gload16(gBq[q], (char*)Bs[0] + (w * 32 + q * 8) * 128);
  }
  asm volatile("s_waitcnt vmcnt(0)" ::: "memory");
  __builtin_amdgcn_s_barrier();

#pragma unroll
  for (int it = 0; it < DIM / BK; ++it) {   // 16 iters, fully unrolled
    const int cur = it & 1;
    // phase 1: issue next tile's loads (async, land during MFMA)
    if (it + 1 < DIM / BK) {
      const int kt2 = (it + 1) * BK;
#pragma unroll
      for (int q = 0; q < 4; ++q) {
        gload16(gAq[q] + kt2, (char*)As[cur ^ 1] + (w * 32 + q * 8) * 128);
        gload16(gBq[q] + kt2, (char*)Bs[cur ^ 1] + (w * 32 + q * 8) * 128);
      }
    }
    // phase 2: compute current tile
    const char* As_b = (const char*)As[cur];
    const char* Bs_b = (const char*)Bs[cur];
    f16x8 bh[4], bl[4];
#pragma unroll
    for (int j = 0; j < 4; ++j) {
      bh[j] = *(const f16x8*)(Bs_b + rBoff[j]);
      bl[j] = *(const f16x8*)(Bs_b + (rBoff[j] ^ 64));
    }
    __builtin_amdgcn_s_setprio(1);
#pragma unroll
    for (int i = 0; i < 4; ++i) {
      f16x8 ah = *(const f16x8*)(As_b + rAoff[i]);
      f16x8 al = *(const f16x8*)(As_b + (rAoff[i] ^ 64));
#pragma unroll
      for (int j = 0; j < 4; ++j) {
        ahh[i][j] = __builtin_amdgcn_mfma_f32_16x16x32_f16(ah, bh[j], ahh[i][j], 0, 0, 0);
        axx[i][j] = __builtin_amdgcn_mfma_f32_16x16x32_f16(ah, bl[j], axx[i][j], 0, 0, 0);
        axx[i][j] = __builtin_amdgcn_mfma_f32_16x16x32_f16(al, bh[j], axx[i][j], 0, 0, 0);
      }
    }
    __builtin_amdgcn_s_setprio(0);
    // phase 3: next tile's loads done + all waves finished reading cur
    asm volatile("s_waitcnt vmcnt(0)" ::: "memory");
    __builtin_amdgcn_s_barrier();
  }

  // epilogue: D row = (lane>>4)*4 + reg, col = lane&15 (m89-verified mapping)
  float c2v[4];
  int   cgv[4];
#pragma unroll
  for (int j = 0; j < 4; ++j) {
    cgv[j] = tn0 + wn * 64 + j * 16 + fr;
    c2v[j] = c2[cgv[j]];
  }
  unsigned long long rmin[4][4];
#pragma unroll
  for (int i = 0; i < 4; ++i)
#pragma unroll
    for (int q = 0; q < 4; ++q) {
      unsigned long long m = ~0ull;
#pragma unroll
      for (int j = 0; j < 4; ++j) {
        float v = c2v[j] - 2.0f * (ahh[i][j][q] + axx[i][j][q] * LOSCI);
        unsigned long long p =
            ((unsigned long long)fkey(v) << 32) | (unsigned int)cgv[j];
        if (p < m) m = p;
      }
#pragma unroll
      for (int d = 1; d < 16; d <<= 1) {
        unsigned long long o = __shfl_xor(m, d, 64);
        if (o < m) m = o;
      }
      rmin[i][q] = m;
    }
  __syncthreads();
  unsigned long long* red = (unsigned long long*)As;   // 2 x 128 u64 = 2 KB
  if (fr == 0) {
#pragma unroll
    for (int i = 0; i < 4; ++i)
#pragma unroll
      for (int q = 0; q < 4; ++q)
        red[wn * 128 + wm * 64 + i * 16 + fq * 4 + q] = rmin[i][q];
  }
  __syncthreads();
  if (t < 128) {
    unsigned long long a = red[t], b = red[128 + t];
    if (b < a) a = b;
    atomicMin(&best[tm0 + t], a);
  }
}

// ---------------------------------------------------------------------------
// Kernel C v2: gather + STE + indices + commit loss.  16 rows per block,
// wave partials -> LDS -> ONE atomicAdd per block (512 total).
// ---------------------------------------------------------------------------
__global__ __launch_bounds__(256) void k_gather(
    const float* __restrict__ x, const float* __restrict__ imp,
    const unsigned long long* __restrict__ best,
    float* __restrict__ out_q, float* __restrict__ out_idx,
    float* __restrict__ out_loss) {
  __shared__ float part[4];
  const int wave = threadIdx.x >> 6;
  const int lane = threadIdx.x & 63;
  float s = 0.f;
#pragma unroll
  for (int rr = 0; rr < 4; ++rr) {
    const int r = blockIdx.x * 16 + wave * 4 + rr;
    const unsigned long long p = best[r];
    const int idx = (int)(p & 0xffffffffu);
    const float4* xr = (const float4*)(x   + (size_t)r   * DIM);
    const float4* qr = (const float4*)(imp + (size_t)idx * DIM);
    float4*       o  = (float4*)(out_q + (size_t)r * DIM);
#pragma unroll
    for (int jh = 0; jh < 2; ++jh) {
      float4 xv = xr[lane + jh * 64];
      float4 qv = qr[lane + jh * 64];
      float4 ov;
      ov.x = xv.x + (qv.x - xv.x);  ov.y = xv.y + (qv.y - xv.y);
      ov.z = xv.z + (qv.z - xv.z);  ov.w = xv.w + (qv.w - xv.w);
      o[lane + jh * 64] = ov;
      float dx = xv.x - qv.x, dy = xv.y - qv.y, dz = xv.z - qv.z, dw = xv.w - qv.w;
      s += dx*dx + dy*dy + dz*dz + dw*dw;
    }
    if (lane == 0) out_idx[r] = (float)idx;
  }
#pragma unroll
  for (int off = 32; off > 0; off >>= 1) s += __shfl_down(s, off);
  if (lane == 0) part[wave] = s;
  __syncthreads();
  if (threadIdx.x == 0) {
    float tot = (part[0] + part[1]) + (part[2] + part[3]);
    atomicAdd(out_loss, tot * (1.0f / (float)BN));
  }
}

// ---------------------------------------------------------------------------
extern "C" void kernel_launch(void* const* d_in, const int* in_sizes, int n_in,
                              void* d_out, int out_size, void* d_ws, size_t ws_size,
                              hipStream_t stream) {
  const float* x  = (const float*)d_in[0];  // [4,2048,512]
  const float* Wm = (const float*)d_in[1];  // [512,512]
  const float* cb = (const float*)d_in[2];  // [8192,512]

  float* out   = (float*)d_out;
  float* out_q = out;
  float* out_i = out + (size_t)BN * DIM;
  float* out_l = out + (size_t)BN * DIM + BN;

  char* ws = (char*)d_ws;
  float* imp = (float*)ws;                                   // 16 MiB
  float* c2  = (float*)(ws + 16777216);                      // 32 KiB
  unsigned long long* best = (unsigned long long*)(ws + 16777216 + 32768);  // 64 KiB
  _Float16* xh = (_Float16*)(ws + 16875520);                 // 8 MiB each
  _Float16* xl = (_Float16*)(ws + 16875520 + 8388608);
  _Float16* ih = (_Float16*)(ws + 16875520 + 2 * 8388608);
  _Float16* il = (_Float16*)(ws + 16875520 + 3 * 8388608);

  hipMemsetAsync(c2, 0, CBSZ * sizeof(float), stream);
  hipMemsetAsync(best, 0xFF, CBSZ * sizeof(unsigned long long), stream);
  hipMemsetAsync(out_l, 0, sizeof(float), stream);

  k_split<<<(BN * DIM / 8) / 256, 256, 0, stream>>>(x, xh, xl);

  dim3 gA(CBSZ / 128, DIM / 128);   // 64 x 4
  k_implicit<<<gA, 256, 0, stream>>>(cb, Wm, imp, ih, il, c2);

  dim3 gB(BN / 128, CBSZ / 128);    // 64 x 64
  k_argmin<<<gB, 256, 0, stream>>>(xh, xl, ih, il, c2, best);

  k_gather<<<BN / 16, 256, 0, stream>>>(x, imp, best, out_q, out_i, out_l);
}

// Round 11
// 402.655 us; speedup vs baseline: 1.0267x; 1.0267x over previous
//
#include <hip/hip_runtime.h>
#include <stdint.h>

#define DIM   512
#define CBSZ  8192
#define BN    8192
#define LDSS  132       // f32 GEMM pad (k_implicit, unchanged structure)

#define LOSC  4096.0f   // residual scale 2^12 (keeps f16 residuals normal)
#define LOSCI (1.0f/4096.0f)
#define BK    32        // k-tile (f16 elems), double-buffered

typedef _Float16 f16x8 __attribute__((ext_vector_type(8)));
typedef _Float16 f16x4 __attribute__((ext_vector_type(4)));
typedef float    f32x4 __attribute__((ext_vector_type(4)));

// Monotone float->uint mapping: float order == unsigned order.
__device__ __forceinline__ unsigned int fkey(float v) {
  unsigned int u = __float_as_uint(v);
  return (u & 0x80000000u) ? ~u : (u | 0x80000000u);
}

// async global->LDS, 16 B per lane; LDS dest = wave-uniform base + lane*16
__device__ __forceinline__ void gload16(const void* g, void* l) {
  __builtin_amdgcn_global_load_lds(
      (const __attribute__((address_space(1))) void*)g,
      (__attribute__((address_space(3))) void*)l, 16, 0, 0);
}

// ---------------------------------------------------------------------------
// Split x (f32) into hi/lo f16 arrays (lo scaled by 2^12).
// ---------------------------------------------------------------------------
__global__ __launch_bounds__(256) void k_split(
    const float* __restrict__ in, _Float16* __restrict__ hi,
    _Float16* __restrict__ lo) {
  const int t = blockIdx.x * 256 + threadIdx.x;
  const float4* p = (const float4*)in + (size_t)t * 2;
  float4 v0 = p[0], v1 = p[1];
  float vv[8] = {v0.x, v0.y, v0.z, v0.w, v1.x, v1.y, v1.z, v1.w};
  f16x8 h, l;
#pragma unroll
  for (int j = 0; j < 8; ++j) {
    h[j] = (_Float16)vv[j];
    l[j] = (_Float16)((vv[j] - (float)h[j]) * LOSC);
  }
  *(f16x8*)(hi + (size_t)t * 8) = h;
  *(f16x8*)(lo + (size_t)t * 8) = l;
}

// ---------------------------------------------------------------------------
// Kernel A: implicit = codebook @ W^T (f32 vector GEMM, bit-matches XLA ref),
// epilogue also writes hi/lo f16 split of implicit + accumulates c2.
// ---------------------------------------------------------------------------
__global__ __launch_bounds__(256) void k_implicit(
    const float* __restrict__ cb, const float* __restrict__ Wm,
    float* __restrict__ imp, _Float16* __restrict__ imph,
    _Float16* __restrict__ impl, float* __restrict__ c2) {
  __shared__ float As[32][LDSS];
  __shared__ float Bs[32][LDSS];
  const int t  = threadIdx.x;
  const int tx = t & 15, ty = t >> 4;
  const int tm0 = blockIdx.x * 128;
  const int tn0 = blockIdx.y * 128;
  float acc[8][8];
#pragma unroll
  for (int i = 0; i < 8; ++i)
#pragma unroll
    for (int j = 0; j < 8; ++j) acc[i][j] = 0.f;

  const int chunk = t & 7, row0 = t >> 3;
  for (int kt = 0; kt < DIM; kt += 32) {
#pragma unroll
    for (int rr = 0; rr < 4; ++rr) {
      int row = row0 + rr * 32;
      float4 av = *(const float4*)(cb + (size_t)(tm0 + row) * DIM + kt + chunk * 4);
      float4 bv = *(const float4*)(Wm + (size_t)(tn0 + row) * DIM + kt + chunk * 4);
      As[chunk*4+0][row] = av.x; As[chunk*4+1][row] = av.y;
      As[chunk*4+2][row] = av.z; As[chunk*4+3][row] = av.w;
      Bs[chunk*4+0][row] = bv.x; Bs[chunk*4+1][row] = bv.y;
      Bs[chunk*4+2][row] = bv.z; Bs[chunk*4+3][row] = bv.w;
    }
    __syncthreads();
#pragma unroll
    for (int k = 0; k < 32; ++k) {
      float4 a0 = *(const float4*)&As[k][ty * 4];
      float4 a1 = *(const float4*)&As[k][64 + ty * 4];
      float4 b0 = *(const float4*)&Bs[k][tx * 4];
      float4 b1 = *(const float4*)&Bs[k][64 + tx * 4];
      float av[8] = {a0.x, a0.y, a0.z, a0.w, a1.x, a1.y, a1.z, a1.w};
      float bv[8] = {b0.x, b0.y, b0.z, b0.w, b1.x, b1.y, b1.z, b1.w};
#pragma unroll
      for (int i = 0; i < 8; ++i)
#pragma unroll
        for (int j = 0; j < 8; ++j) acc[i][j] = fmaf(av[i], bv[j], acc[i][j]);
    }
    __syncthreads();
  }
#pragma unroll
  for (int i = 0; i < 8; ++i) {
    int rl = ((i >> 2) << 6) + ty * 4 + (i & 3);
    int rg = tm0 + rl;
    float s = 0.f;
#pragma unroll
    for (int jh = 0; jh < 2; ++jh) {
      float4 v = make_float4(acc[i][jh*4+0], acc[i][jh*4+1], acc[i][jh*4+2], acc[i][jh*4+3]);
      int cg = tn0 + (jh << 6) + tx * 4;
      *(float4*)(imp + (size_t)rg * DIM + cg) = v;
      float vs[4] = {v.x, v.y, v.z, v.w};
      f16x4 vh, vl;
#pragma unroll
      for (int q = 0; q < 4; ++q) {
        vh[q] = (_Float16)vs[q];
        vl[q] = (_Float16)((vs[q] - (float)vh[q]) * LOSC);
      }
      *(f16x4*)(imph + (size_t)rg * DIM + cg) = vh;
      *(f16x4*)(impl + (size_t)rg * DIM + cg) = vl;
      s += v.x*v.x + v.y*v.y + v.z*v.z + v.w*v.w;
    }
    atomicAdd(&c2[rg], s);
  }
}

// ---------------------------------------------------------------------------
// Kernel B v6: fused x @ implicit^T + per-row argmin, f16-split 3-pass MFMA.
// 2-phase dbuf pipeline, alias-hazard-free ordering: per iteration
//   (1) ds_read ALL fragments of buf[cur] into registers,
//   (2) issue next tile's global_load_lds into buf[cur^1],
//   (3) sched_barrier(0) pins issue order,
//   (4) 48-MFMA cluster covers the load latency,
//   (5) vmcnt(0) + s_barrier.
// No ds_read follows a gload in program order, and at ds_read time vmcnt==0
// (previous iter drained) -> the r9 conservative-wait serializer cannot
// trigger.  LDS layout = r7-validated XOR swizzle; k-order unchanged ->
// bit-identical results.
// ---------------------------------------------------------------------------
__global__ __launch_bounds__(256, 2) void k_argmin(
    const _Float16* __restrict__ xh, const _Float16* __restrict__ xl,
    const _Float16* __restrict__ ch, const _Float16* __restrict__ cl,
    const float* __restrict__ c2, unsigned long long* __restrict__ best) {
  __shared__ _Float16 As[2][128 * 64];   // 16 KB x2
  __shared__ _Float16 Bs[2][128 * 64];   // 16 KB x2
  const int t    = threadIdx.x;
  const int lane = t & 63, w = t >> 6;
  const int wm = w >> 1, wn = w & 1;
  const int fr = lane & 15, fq = lane >> 4;
  const int tm0 = blockIdx.x * 128;   // x rows
  const int tn0 = blockIdx.y * 128;   // codebook entries

  f32x4 ahh[4][4], axx[4][4];
#pragma unroll
  for (int i = 0; i < 4; ++i)
#pragma unroll
    for (int j = 0; j < 4; ++j) {
      ahh[i][j] = (f32x4){0.f, 0.f, 0.f, 0.f};
      axx[i][j] = (f32x4){0.f, 0.f, 0.f, 0.f};
    }

  // staging: lane l -> row (l>>3), physical slot (l&7); logical slot
  // s = (l&7)^(l>>3); s&4 -> lo array, s&3 -> 16 B k-chunk.
  const int s_   = (lane & 7) ^ (lane >> 3);
  const int rofs = lane >> 3;
  const _Float16* baseA = (s_ & 4) ? xl : xh;
  const _Float16* baseB = (s_ & 4) ? cl : ch;
  const _Float16* gAq[4];
  const _Float16* gBq[4];
#pragma unroll
  for (int q = 0; q < 4; ++q) {
    int rA = tm0 + w * 32 + q * 8 + rofs;
    int rB = tn0 + w * 32 + q * 8 + rofs;
    gAq[q] = baseA + (size_t)rA * DIM + (s_ & 3) * 8;
    gBq[q] = baseB + (size_t)rB * DIM + (s_ & 3) * 8;
  }

  // fragment read byte offsets (k-invariant); lo fragment = hi ^ 64
  int rAoff[4], rBoff[4];
#pragma unroll
  for (int i = 0; i < 4; ++i) {
    rAoff[i] = (wm * 64 + i * 16 + fr) * 128 + ((fq ^ (fr & 7)) << 4);
    rBoff[i] = (wn * 64 + i * 16 + fr) * 128 + ((fq ^ (fr & 7)) << 4);
  }

  // prologue: stage tile 0 into buffer 0, drain, sync
#pragma unroll
  for (int q = 0; q < 4; ++q) {
    gload16(gAq[q], (char*)As[0] + (w * 32 + q * 8) * 128);
    gload16(gBq[q], (char*)Bs[0] + (w * 32 + q * 8) * 128);
  }
  asm volatile("s_waitcnt vmcnt(0)" ::: "memory");
  __builtin_amdgcn_s_barrier();

#pragma unroll 2
  for (int it = 0; it < DIM / BK; ++it) {   // 16 iters
    const int cur = it & 1;
    const char* As_b = (const char*)As[cur];
    const char* Bs_b = (const char*)Bs[cur];
    // (1) read ALL fragments of current tile into registers first
    f16x8 bh[4], bl[4], ah[4], al[4];
#pragma unroll
    for (int j = 0; j < 4; ++j) {
      bh[j] = *(const f16x8*)(Bs_b + rBoff[j]);
      bl[j] = *(const f16x8*)(Bs_b + (rBoff[j] ^ 64));
    }
#pragma unroll
    for (int i = 0; i < 4; ++i) {
      ah[i] = *(const f16x8*)(As_b + rAoff[i]);
      al[i] = *(const f16x8*)(As_b + (rAoff[i] ^ 64));
    }
    // (2) issue next tile's loads (async; land during MFMA cluster)
    if (it + 1 < DIM / BK) {
      const int kt2 = (it + 1) * BK;
#pragma unroll
      for (int q = 0; q < 4; ++q) {
        gload16(gAq[q] + kt2, (char*)As[cur ^ 1] + (w * 32 + q * 8) * 128);
        gload16(gBq[q] + kt2, (char*)Bs[cur ^ 1] + (w * 32 + q * 8) * 128);
      }
    }
    // (3) pin order: loads issued before the MFMA cluster
    __builtin_amdgcn_sched_barrier(0);
    // (4) MFMA cluster (register-only; covers load latency)
#pragma unroll
    for (int i = 0; i < 4; ++i)
#pragma unroll
      for (int j = 0; j < 4; ++j) {
        ahh[i][j] = __builtin_amdgcn_mfma_f32_16x16x32_f16(ah[i], bh[j], ahh[i][j], 0, 0, 0);
        axx[i][j] = __builtin_amdgcn_mfma_f32_16x16x32_f16(ah[i], bl[j], axx[i][j], 0, 0, 0);
        axx[i][j] = __builtin_amdgcn_mfma_f32_16x16x32_f16(al[i], bh[j], axx[i][j], 0, 0, 0);
      }
    // (5) next tile resident + everyone done reading cur
    asm volatile("s_waitcnt vmcnt(0)" ::: "memory");
    __builtin_amdgcn_s_barrier();
  }

  // epilogue: D row = (lane>>4)*4 + reg, col = lane&15 (m89-verified mapping)
  float c2v[4];
  int   cgv[4];
#pragma unroll
  for (int j = 0; j < 4; ++j) {
    cgv[j] = tn0 + wn * 64 + j * 16 + fr;
    c2v[j] = c2[cgv[j]];
  }
  unsigned long long rmin[4][4];
#pragma unroll
  for (int i = 0; i < 4; ++i)
#pragma unroll
    for (int q = 0; q < 4; ++q) {
      unsigned long long m = ~0ull;
#pragma unroll
      for (int j = 0; j < 4; ++j) {
        float v = c2v[j] - 2.0f * (ahh[i][j][q] + axx[i][j][q] * LOSCI);
        unsigned long long p =
            ((unsigned long long)fkey(v) << 32) | (unsigned int)cgv[j];
        if (p < m) m = p;
      }
#pragma unroll
      for (int d = 1; d < 16; d <<= 1) {
        unsigned long long o = __shfl_xor(m, d, 64);
        if (o < m) m = o;
      }
      rmin[i][q] = m;
    }
  __syncthreads();
  unsigned long long* red = (unsigned long long*)As;   // 2 x 128 u64 = 2 KB
  if (fr == 0) {
#pragma unroll
    for (int i = 0; i < 4; ++i)
#pragma unroll
      for (int q = 0; q < 4; ++q)
        red[wn * 128 + wm * 64 + i * 16 + fq * 4 + q] = rmin[i][q];
  }
  __syncthreads();
  if (t < 128) {
    unsigned long long a = red[t], b = red[128 + t];
    if (b < a) a = b;
    atomicMin(&best[tm0 + t], a);
  }
}

// ---------------------------------------------------------------------------
// Kernel C v2: gather + STE + indices + commit loss.  16 rows per block,
// wave partials -> LDS -> ONE atomicAdd per block (512 total).
// ---------------------------------------------------------------------------
__global__ __launch_bounds__(256) void k_gather(
    const float* __restrict__ x, const float* __restrict__ imp,
    const unsigned long long* __restrict__ best,
    float* __restrict__ out_q, float* __restrict__ out_idx,
    float* __restrict__ out_loss) {
  __shared__ float part[4];
  const int wave = threadIdx.x >> 6;
  const int lane = threadIdx.x & 63;
  float s = 0.f;
#pragma unroll
  for (int rr = 0; rr < 4; ++rr) {
    const int r = blockIdx.x * 16 + wave * 4 + rr;
    const unsigned long long p = best[r];
    const int idx = (int)(p & 0xffffffffu);
    const float4* xr = (const float4*)(x   + (size_t)r   * DIM);
    const float4* qr = (const float4*)(imp + (size_t)idx * DIM);
    float4*       o  = (float4*)(out_q + (size_t)r * DIM);
#pragma unroll
    for (int jh = 0; jh < 2; ++jh) {
      float4 xv = xr[lane + jh * 64];
      float4 qv = qr[lane + jh * 64];
      float4 ov;
      ov.x = xv.x + (qv.x - xv.x);  ov.y = xv.y + (qv.y - xv.y);
      ov.z = xv.z + (qv.z - xv.z);  ov.w = xv.w + (qv.w - xv.w);
      o[lane + jh * 64] = ov;
      float dx = xv.x - qv.x, dy = xv.y - qv.y, dz = xv.z - qv.z, dw = xv.w - qv.w;
      s += dx*dx + dy*dy + dz*dz + dw*dw;
    }
    if (lane == 0) out_idx[r] = (float)idx;
  }
#pragma unroll
  for (int off = 32; off > 0; off >>= 1) s += __shfl_down(s, off);
  if (lane == 0) part[wave] = s;
  __syncthreads();
  if (threadIdx.x == 0) {
    float tot = (part[0] + part[1]) + (part[2] + part[3]);
    atomicAdd(out_loss, tot * (1.0f / (float)BN));
  }
}

// ---------------------------------------------------------------------------
extern "C" void kernel_launch(void* const* d_in, const int* in_sizes, int n_in,
                              void* d_out, int out_size, void* d_ws, size_t ws_size,
                              hipStream_t stream) {
  const float* x  = (const float*)d_in[0];  // [4,2048,512]
  const float* Wm = (const float*)d_in[1];  // [512,512]
  const float* cb = (const float*)d_in[2];  // [8192,512]

  float* out   = (float*)d_out;
  float* out_q = out;
  float* out_i = out + (size_t)BN * DIM;
  float* out_l = out + (size_t)BN * DIM + BN;

  char* ws = (char*)d_ws;
  float* imp = (float*)ws;                                   // 16 MiB
  float* c2  = (float*)(ws + 16777216);                      // 32 KiB
  unsigned long long* best = (unsigned long long*)(ws + 16777216 + 32768);  // 64 KiB
  _Float16* xh = (_Float16*)(ws + 16875520);                 // 8 MiB each
  _Float16* xl = (_Float16*)(ws + 16875520 + 8388608);
  _Float16* ih = (_Float16*)(ws + 16875520 + 2 * 8388608);
  _Float16* il = (_Float16*)(ws + 16875520 + 3 * 8388608);

  hipMemsetAsync(c2, 0, CBSZ * sizeof(float), stream);
  hipMemsetAsync(best, 0xFF, CBSZ * sizeof(unsigned long long), stream);
  hipMemsetAsync(out_l, 0, sizeof(float), stream);

  k_split<<<(BN * DIM / 8) / 256, 256, 0, stream>>>(x, xh, xl);

  dim3 gA(CBSZ / 128, DIM / 128);   // 64 x 4
  k_implicit<<<gA, 256, 0, stream>>>(cb, Wm, imp, ih, il, c2);

  dim3 gB(BN / 128, CBSZ / 128);    // 64 x 64
  k_argmin<<<gB, 256, 0, stream>>>(xh, xl, ih, il, c2, best);

  k_gather<<<BN / 16, 256, 0, stream>>>(x, imp, best, out_q, out_i, out_l);
}

// Round 12
// 336.279 us; speedup vs baseline: 1.2294x; 1.1974x over previous
//
#include <hip/hip_runtime.h>
#include <stdint.h>

#define DIM   512
#define CBSZ  8192
#define BN    8192

#define LOSC  4096.0f   // residual scale 2^12 (keeps f16 residuals normal)
#define LOSCI (1.0f/4096.0f)
#define BK    64        // k-tile (f16 elems), r8-validated single-buffer

typedef _Float16 f16x8 __attribute__((ext_vector_type(8)));
typedef float    f32x4 __attribute__((ext_vector_type(4)));

// Monotone float->uint mapping: float order == unsigned order.
__device__ __forceinline__ unsigned int fkey(float v) {
  unsigned int u = __float_as_uint(v);
  return (u & 0x80000000u) ? ~u : (u | 0x80000000u);
}

// async global->LDS, 16 B per lane; LDS dest = wave-uniform base + lane*16
__device__ __forceinline__ void gload16(const void* g, void* l) {
  __builtin_amdgcn_global_load_lds(
      (const __attribute__((address_space(1))) void*)g,
      (__attribute__((address_space(3))) void*)l, 16, 0, 0);
}

// ---------------------------------------------------------------------------
// Split f32 array into hi/lo f16 arrays (lo scaled by 2^12); 8 elems/thread.
// ---------------------------------------------------------------------------
__global__ __launch_bounds__(256) void k_split(
    const float* __restrict__ in, _Float16* __restrict__ hi,
    _Float16* __restrict__ lo) {
  const int t = blockIdx.x * 256 + threadIdx.x;
  const float4* p = (const float4*)in + (size_t)t * 2;
  float4 v0 = p[0], v1 = p[1];
  float vv[8] = {v0.x, v0.y, v0.z, v0.w, v1.x, v1.y, v1.z, v1.w};
  f16x8 h, l;
#pragma unroll
  for (int j = 0; j < 8; ++j) {
    h[j] = (_Float16)vv[j];
    l[j] = (_Float16)((vv[j] - (float)h[j]) * LOSC);
  }
  *(f16x8*)(hi + (size_t)t * 8) = h;
  *(f16x8*)(lo + (size_t)t * 8) = l;
}

// ---------------------------------------------------------------------------
// Kernel A v2 (MFMA): implicit = codebook @ W^T via f16-split 3-pass.
// Same r8-validated GEMM geometry as k_argmin (128x128 tile, BK=64, XOR
// swizzle row=256B/16 slots, global_load_lds staging).  Epilogue writes
// imp (f32 = hh + x/4096), its f16 re-split (imph/impl), and c2 row norms.
// ---------------------------------------------------------------------------
__global__ __launch_bounds__(256, 2) void k_implicit(
    const _Float16* __restrict__ cbh, const _Float16* __restrict__ cbl,
    const _Float16* __restrict__ Wh,  const _Float16* __restrict__ Wl,
    float* __restrict__ imp, _Float16* __restrict__ imph,
    _Float16* __restrict__ impl, float* __restrict__ c2) {
  __shared__ _Float16 As[128 * 128];   // 32 KB (128 rows x 256 B)
  __shared__ _Float16 Bs[128 * 128];   // 32 KB
  const int t    = threadIdx.x;
  const int lane = t & 63, w = t >> 6;
  const int wm = w >> 1, wn = w & 1;
  const int fr = lane & 15, fq = lane >> 4;
  const int tm0 = blockIdx.x * 128;   // codebook rows
  const int tn0 = blockIdx.y * 128;   // W rows (= output cols)

  f32x4 ahh[4][4], axx[4][4];
#pragma unroll
  for (int i = 0; i < 4; ++i)
#pragma unroll
    for (int j = 0; j < 4; ++j) {
      ahh[i][j] = (f32x4){0.f, 0.f, 0.f, 0.f};
      axx[i][j] = (f32x4){0.f, 0.f, 0.f, 0.f};
    }

  const int sBase = (lane & 15) ^ (lane >> 4);
  const int rIn   = lane >> 4;
  char* As_b = (char*)As;
  char* Bs_b = (char*)Bs;

  int rAoff[4], rBoff[4];
#pragma unroll
  for (int i = 0; i < 4; ++i) {
    rAoff[i] = (wm * 64 + i * 16 + fr) * 256 + ((fq ^ fr) << 4);
    rBoff[i] = (wn * 64 + i * 16 + fr) * 256 + ((fq ^ fr) << 4);
  }

  for (int kt = 0; kt < DIM; kt += BK) {
    __syncthreads();
#pragma unroll
    for (int q = 0; q < 8; ++q) {
      const int s    = sBase ^ ((q & 3) << 2);
      const int row  = w * 32 + q * 4 + rIn;
      const int koff = (s >> 3) * 32 + (s & 3) * 8;
      const _Float16* pa =
          ((s & 4) ? cbl : cbh) + (size_t)(tm0 + row) * DIM + kt + koff;
      const _Float16* pb =
          ((s & 4) ? Wl : Wh) + (size_t)(tn0 + row) * DIM + kt + koff;
      gload16(pa, As_b + (w * 32 + q * 4) * 256);
      gload16(pb, Bs_b + (w * 32 + q * 4) * 256);
    }
    __syncthreads();

#pragma unroll
    for (int kk = 0; kk < 2; ++kk) {
      const int kx = kk << 7;
      f16x8 bh[4], bl[4];
#pragma unroll
      for (int j = 0; j < 4; ++j) {
        bh[j] = *(const f16x8*)(Bs_b + (rBoff[j] ^ kx));
        bl[j] = *(const f16x8*)(Bs_b + (rBoff[j] ^ kx ^ 64));
      }
#pragma unroll
      for (int i = 0; i < 4; ++i) {
        f16x8 ah = *(const f16x8*)(As_b + (rAoff[i] ^ kx));
        f16x8 al = *(const f16x8*)(As_b + (rAoff[i] ^ kx ^ 64));
#pragma unroll
        for (int j = 0; j < 4; ++j) {
          ahh[i][j] = __builtin_amdgcn_mfma_f32_16x16x32_f16(ah, bh[j], ahh[i][j], 0, 0, 0);
          axx[i][j] = __builtin_amdgcn_mfma_f32_16x16x32_f16(ah, bl[j], axx[i][j], 0, 0, 0);
          axx[i][j] = __builtin_amdgcn_mfma_f32_16x16x32_f16(al, bh[j], axx[i][j], 0, 0, 0);
        }
      }
    }
  }

  // epilogue: D row (A-side) = fq*4 + q (+16i), col (B-side) = fr (+16j)
#pragma unroll
  for (int i = 0; i < 4; ++i) {
#pragma unroll
    for (int q = 0; q < 4; ++q) {
      const int rg = tm0 + wm * 64 + i * 16 + fq * 4 + q;
      float s2 = 0.f;
#pragma unroll
      for (int j = 0; j < 4; ++j) {
        const int cg = tn0 + wn * 64 + j * 16 + fr;
        float val = ahh[i][j][q] + axx[i][j][q] * LOSCI;
        imp[(size_t)rg * DIM + cg] = val;
        _Float16 vh = (_Float16)val;
        _Float16 vl = (_Float16)((val - (float)vh) * LOSC);
        imph[(size_t)rg * DIM + cg] = vh;
        impl[(size_t)rg * DIM + cg] = vl;
        s2 += val * val;
      }
      // reduce s2 over the 16 lanes (fr) sharing this row
#pragma unroll
      for (int d = 1; d < 16; d <<= 1) s2 += __shfl_xor(s2, d, 64);
      if (fr == 0) atomicAdd(&c2[rg], s2);
    }
  }
}

// ---------------------------------------------------------------------------
// Kernel B (r8-validated, 211 us): fused x @ implicit^T + per-row argmin,
// f16-split 3-pass MFMA, BK=64 single-buffer, XOR-swizzled LDS, gload_lds.
// ---------------------------------------------------------------------------
__global__ __launch_bounds__(256, 2) void k_argmin(
    const _Float16* __restrict__ xh, const _Float16* __restrict__ xl,
    const _Float16* __restrict__ ch, const _Float16* __restrict__ cl,
    const float* __restrict__ c2, unsigned long long* __restrict__ best) {
  __shared__ _Float16 As[128 * 128];   // 32 KB (128 rows x 256 B)
  __shared__ _Float16 Bs[128 * 128];   // 32 KB
  const int t    = threadIdx.x;
  const int lane = t & 63, w = t >> 6;
  const int wm = w >> 1, wn = w & 1;
  const int fr = lane & 15, fq = lane >> 4;
  const int tm0 = blockIdx.x * 128;   // x rows
  const int tn0 = blockIdx.y * 128;   // codebook entries

  f32x4 ahh[4][4], axx[4][4];
#pragma unroll
  for (int i = 0; i < 4; ++i)
#pragma unroll
    for (int j = 0; j < 4; ++j) {
      ahh[i][j] = (f32x4){0.f, 0.f, 0.f, 0.f};
      axx[i][j] = (f32x4){0.f, 0.f, 0.f, 0.f};
    }

  const int sBase = (lane & 15) ^ (lane >> 4);
  const int rIn   = lane >> 4;
  char* As_b = (char*)As;
  char* Bs_b = (char*)Bs;

  int rAoff[4], rBoff[4];
#pragma unroll
  for (int i = 0; i < 4; ++i) {
    rAoff[i] = (wm * 64 + i * 16 + fr) * 256 + ((fq ^ fr) << 4);
    rBoff[i] = (wn * 64 + i * 16 + fr) * 256 + ((fq ^ fr) << 4);
  }

  for (int kt = 0; kt < DIM; kt += BK) {
    __syncthreads();
#pragma unroll
    for (int q = 0; q < 8; ++q) {
      const int s    = sBase ^ ((q & 3) << 2);
      const int row  = w * 32 + q * 4 + rIn;
      const int koff = (s >> 3) * 32 + (s & 3) * 8;
      const _Float16* pa =
          ((s & 4) ? xl : xh) + (size_t)(tm0 + row) * DIM + kt + koff;
      const _Float16* pb =
          ((s & 4) ? cl : ch) + (size_t)(tn0 + row) * DIM + kt + koff;
      gload16(pa, As_b + (w * 32 + q * 4) * 256);
      gload16(pb, Bs_b + (w * 32 + q * 4) * 256);
    }
    __syncthreads();

#pragma unroll
    for (int kk = 0; kk < 2; ++kk) {
      const int kx = kk << 7;
      f16x8 bh[4], bl[4];
#pragma unroll
      for (int j = 0; j < 4; ++j) {
        bh[j] = *(const f16x8*)(Bs_b + (rBoff[j] ^ kx));
        bl[j] = *(const f16x8*)(Bs_b + (rBoff[j] ^ kx ^ 64));
      }
#pragma unroll
      for (int i = 0; i < 4; ++i) {
        f16x8 ah = *(const f16x8*)(As_b + (rAoff[i] ^ kx));
        f16x8 al = *(const f16x8*)(As_b + (rAoff[i] ^ kx ^ 64));
#pragma unroll
        for (int j = 0; j < 4; ++j) {
          ahh[i][j] = __builtin_amdgcn_mfma_f32_16x16x32_f16(ah, bh[j], ahh[i][j], 0, 0, 0);
          axx[i][j] = __builtin_amdgcn_mfma_f32_16x16x32_f16(ah, bl[j], axx[i][j], 0, 0, 0);
          axx[i][j] = __builtin_amdgcn_mfma_f32_16x16x32_f16(al, bh[j], axx[i][j], 0, 0, 0);
        }
      }
    }
  }

  // epilogue: D row = (lane>>4)*4 + reg, col = lane&15 (m89-verified mapping)
  float c2v[4];
  int   cgv[4];
#pragma unroll
  for (int j = 0; j < 4; ++j) {
    cgv[j] = tn0 + wn * 64 + j * 16 + fr;
    c2v[j] = c2[cgv[j]];
  }
  unsigned long long rmin[4][4];
#pragma unroll
  for (int i = 0; i < 4; ++i)
#pragma unroll
    for (int q = 0; q < 4; ++q) {
      unsigned long long m = ~0ull;
#pragma unroll
      for (int j = 0; j < 4; ++j) {
        float v = c2v[j] - 2.0f * (ahh[i][j][q] + axx[i][j][q] * LOSCI);
        unsigned long long p =
            ((unsigned long long)fkey(v) << 32) | (unsigned int)cgv[j];
        if (p < m) m = p;
      }
#pragma unroll
      for (int d = 1; d < 16; d <<= 1) {
        unsigned long long o = __shfl_xor(m, d, 64);
        if (o < m) m = o;
      }
      rmin[i][q] = m;
    }
  __syncthreads();
  unsigned long long* red = (unsigned long long*)As;   // 2 x 128 u64 = 2 KB
  if (fr == 0) {
#pragma unroll
    for (int i = 0; i < 4; ++i)
#pragma unroll
      for (int q = 0; q < 4; ++q)
        red[wn * 128 + wm * 64 + i * 16 + fq * 4 + q] = rmin[i][q];
  }
  __syncthreads();
  if (t < 128) {
    unsigned long long a = red[t], b = red[128 + t];
    if (b < a) a = b;
    atomicMin(&best[tm0 + t], a);
  }
}

// ---------------------------------------------------------------------------
// Kernel C v2: gather + STE + indices + commit loss.  16 rows per block,
// wave partials -> LDS -> ONE atomicAdd per block (512 total).
// ---------------------------------------------------------------------------
__global__ __launch_bounds__(256) void k_gather(
    const float* __restrict__ x, const float* __restrict__ imp,
    const unsigned long long* __restrict__ best,
    float* __restrict__ out_q, float* __restrict__ out_idx,
    float* __restrict__ out_loss) {
  __shared__ float part[4];
  const int wave = threadIdx.x >> 6;
  const int lane = threadIdx.x & 63;
  float s = 0.f;
#pragma unroll
  for (int rr = 0; rr < 4; ++rr) {
    const int r = blockIdx.x * 16 + wave * 4 + rr;
    const unsigned long long p = best[r];
    const int idx = (int)(p & 0xffffffffu);
    const float4* xr = (const float4*)(x   + (size_t)r   * DIM);
    const float4* qr = (const float4*)(imp + (size_t)idx * DIM);
    float4*       o  = (float4*)(out_q + (size_t)r * DIM);
#pragma unroll
    for (int jh = 0; jh < 2; ++jh) {
      float4 xv = xr[lane + jh * 64];
      float4 qv = qr[lane + jh * 64];
      float4 ov;
      ov.x = xv.x + (qv.x - xv.x);  ov.y = xv.y + (qv.y - xv.y);
      ov.z = xv.z + (qv.z - xv.z);  ov.w = xv.w + (qv.w - xv.w);
      o[lane + jh * 64] = ov;
      float dx = xv.x - qv.x, dy = xv.y - qv.y, dz = xv.z - qv.z, dw = xv.w - qv.w;
      s += dx*dx + dy*dy + dz*dz + dw*dw;
    }
    if (lane == 0) out_idx[r] = (float)idx;
  }
#pragma unroll
  for (int off = 32; off > 0; off >>= 1) s += __shfl_down(s, off);
  if (lane == 0) part[wave] = s;
  __syncthreads();
  if (threadIdx.x == 0) {
    float tot = (part[0] + part[1]) + (part[2] + part[3]);
    atomicAdd(out_loss, tot * (1.0f / (float)BN));
  }
}

// ---------------------------------------------------------------------------
extern "C" void kernel_launch(void* const* d_in, const int* in_sizes, int n_in,
                              void* d_out, int out_size, void* d_ws, size_t ws_size,
                              hipStream_t stream) {
  const float* x  = (const float*)d_in[0];  // [4,2048,512]
  const float* Wm = (const float*)d_in[1];  // [512,512]
  const float* cb = (const float*)d_in[2];  // [8192,512]

  float* out   = (float*)d_out;
  float* out_q = out;
  float* out_i = out + (size_t)BN * DIM;
  float* out_l = out + (size_t)BN * DIM + BN;

  char* ws = (char*)d_ws;
  float* imp = (float*)ws;                                            // 16 MiB
  float* c2  = (float*)(ws + 16777216);                               // 32 KiB
  unsigned long long* best = (unsigned long long*)(ws + 16809984);    // 64 KiB
  _Float16* xh  = (_Float16*)(ws + 16875520);                         // 8 MiB
  _Float16* xl  = (_Float16*)(ws + 16875520 + 1 * 8388608);
  _Float16* ih  = (_Float16*)(ws + 16875520 + 2 * 8388608);
  _Float16* il  = (_Float16*)(ws + 16875520 + 3 * 8388608);
  _Float16* cbh = (_Float16*)(ws + 16875520 + 4 * 8388608);
  _Float16* cbl = (_Float16*)(ws + 16875520 + 5 * 8388608);
  _Float16* Wh  = (_Float16*)(ws + 16875520 + 6 * 8388608);           // 512 KiB
  _Float16* Wl  = (_Float16*)(ws + 16875520 + 6 * 8388608 + 524288);  // 512 KiB

  hipMemsetAsync(c2, 0, CBSZ * sizeof(float), stream);
  hipMemsetAsync(best, 0xFF, CBSZ * sizeof(unsigned long long), stream);
  hipMemsetAsync(out_l, 0, sizeof(float), stream);

  k_split<<<(BN * DIM / 8) / 256, 256, 0, stream>>>(x, xh, xl);
  k_split<<<(CBSZ * DIM / 8) / 256, 256, 0, stream>>>(cb, cbh, cbl);
  k_split<<<(DIM * DIM / 8) / 256, 256, 0, stream>>>(Wm, Wh, Wl);

  dim3 gA(CBSZ / 128, DIM / 128);   // 64 x 4
  k_implicit<<<gA, 256, 0, stream>>>(cbh, cbl, Wh, Wl, imp, ih, il, c2);

  dim3 gB(BN / 128, CBSZ / 128);    // 64 x 64
  k_argmin<<<gB, 256, 0, stream>>>(xh, xl, ih, il, c2, best);

  k_gather<<<BN / 16, 256, 0, stream>>>(x, imp, best, out_q, out_i, out_l);
}

// Round 13
// 328.564 us; speedup vs baseline: 1.2582x; 1.0235x over previous
//
#include <hip/hip_runtime.h>
#include <stdint.h>

#define DIM   512
#define CBSZ  8192
#define BN    8192

#define LOSC  4096.0f   // residual scale 2^12 (keeps f16 residuals normal)
#define LOSCI (1.0f/4096.0f)
#define BK    64        // k-tile (f16 elems), r8-validated single-buffer

typedef _Float16 f16x8 __attribute__((ext_vector_type(8)));
typedef float    f32x4 __attribute__((ext_vector_type(4)));

// Monotone float->uint mapping: float order == unsigned order.
__device__ __forceinline__ unsigned int fkey(float v) {
  unsigned int u = __float_as_uint(v);
  return (u & 0x80000000u) ? ~u : (u | 0x80000000u);
}

// async global->LDS, 16 B per lane; LDS dest = wave-uniform base + lane*16
__device__ __forceinline__ void gload16(const void* g, void* l) {
  __builtin_amdgcn_global_load_lds(
      (const __attribute__((address_space(1))) void*)g,
      (__attribute__((address_space(3))) void*)l, 16, 0, 0);
}

// ---------------------------------------------------------------------------
// k_prep: fused input prep.  Blocks [0,2048) split x, [2048,4096) split cb,
// [4096,4224) split W (8 f32 -> hi/lo f16 per thread); blocks [4224,4256)
// init c2 (0), best (0xFF..), out_l (0).  Replaces 3 k_split + 3 memset
// dispatches (launch-gap reduction).
// ---------------------------------------------------------------------------
__global__ __launch_bounds__(256) void k_prep(
    const float* __restrict__ x,  _Float16* __restrict__ xh,  _Float16* __restrict__ xl,
    const float* __restrict__ cb, _Float16* __restrict__ cbh, _Float16* __restrict__ cbl,
    const float* __restrict__ Wm, _Float16* __restrict__ Wh,  _Float16* __restrict__ Wl,
    float* __restrict__ c2, unsigned long long* __restrict__ best,
    float* __restrict__ out_l) {
  const int bid = blockIdx.x;
  if (bid < 4224) {
    const float* in; _Float16* hi; _Float16* lo; size_t u;
    if (bid < 2048)      { in = x;  hi = xh;  lo = xl;  u = (size_t)bid * 256 + threadIdx.x; }
    else if (bid < 4096) { in = cb; hi = cbh; lo = cbl; u = (size_t)(bid - 2048) * 256 + threadIdx.x; }
    else                 { in = Wm; hi = Wh;  lo = Wl;  u = (size_t)(bid - 4096) * 256 + threadIdx.x; }
    const float4* p = (const float4*)in + u * 2;
    float4 v0 = p[0], v1 = p[1];
    float vv[8] = {v0.x, v0.y, v0.z, v0.w, v1.x, v1.y, v1.z, v1.w};
    f16x8 h, l;
#pragma unroll
    for (int j = 0; j < 8; ++j) {
      h[j] = (_Float16)vv[j];
      l[j] = (_Float16)((vv[j] - (float)h[j]) * LOSC);
    }
    *(f16x8*)(hi + u * 8) = h;
    *(f16x8*)(lo + u * 8) = l;
  } else {
    const int t = (bid - 4224) * 256 + threadIdx.x;   // 0..8191
    c2[t] = 0.f;
    best[t] = ~0ull;
    if (t == 0) *out_l = 0.f;
  }
}

// ---------------------------------------------------------------------------
// Kernel A (MFMA, r12-validated): implicit = codebook @ W^T, f16-split 3-pass.
// 128x128 tile, BK=64, XOR swizzle (row=256B/16 slots), gload_lds staging.
// Epilogue writes imp (f32), its f16 re-split, and c2 row norms.
// ---------------------------------------------------------------------------
__global__ __launch_bounds__(256, 2) void k_implicit(
    const _Float16* __restrict__ cbh, const _Float16* __restrict__ cbl,
    const _Float16* __restrict__ Wh,  const _Float16* __restrict__ Wl,
    float* __restrict__ imp, _Float16* __restrict__ imph,
    _Float16* __restrict__ impl, float* __restrict__ c2) {
  __shared__ _Float16 As[128 * 128];   // 32 KB (128 rows x 256 B)
  __shared__ _Float16 Bs[128 * 128];   // 32 KB
  const int t    = threadIdx.x;
  const int lane = t & 63, w = t >> 6;
  const int wm = w >> 1, wn = w & 1;
  const int fr = lane & 15, fq = lane >> 4;
  const int tm0 = blockIdx.x * 128;   // codebook rows
  const int tn0 = blockIdx.y * 128;   // W rows (= output cols)

  f32x4 ahh[4][4], axx[4][4];
#pragma unroll
  for (int i = 0; i < 4; ++i)
#pragma unroll
    for (int j = 0; j < 4; ++j) {
      ahh[i][j] = (f32x4){0.f, 0.f, 0.f, 0.f};
      axx[i][j] = (f32x4){0.f, 0.f, 0.f, 0.f};
    }

  const int sBase = (lane & 15) ^ (lane >> 4);
  const int rIn   = lane >> 4;
  char* As_b = (char*)As;
  char* Bs_b = (char*)Bs;

  int rAoff[4], rBoff[4];
#pragma unroll
  for (int i = 0; i < 4; ++i) {
    rAoff[i] = (wm * 64 + i * 16 + fr) * 256 + ((fq ^ fr) << 4);
    rBoff[i] = (wn * 64 + i * 16 + fr) * 256 + ((fq ^ fr) << 4);
  }

  for (int kt = 0; kt < DIM; kt += BK) {
    __syncthreads();
#pragma unroll
    for (int q = 0; q < 8; ++q) {
      const int s    = sBase ^ ((q & 3) << 2);
      const int row  = w * 32 + q * 4 + rIn;
      const int koff = (s >> 3) * 32 + (s & 3) * 8;
      const _Float16* pa =
          ((s & 4) ? cbl : cbh) + (size_t)(tm0 + row) * DIM + kt + koff;
      const _Float16* pb =
          ((s & 4) ? Wl : Wh) + (size_t)(tn0 + row) * DIM + kt + koff;
      gload16(pa, As_b + (w * 32 + q * 4) * 256);
      gload16(pb, Bs_b + (w * 32 + q * 4) * 256);
    }
    __syncthreads();

#pragma unroll
    for (int kk = 0; kk < 2; ++kk) {
      const int kx = kk << 7;
      f16x8 bh[4], bl[4];
#pragma unroll
      for (int j = 0; j < 4; ++j) {
        bh[j] = *(const f16x8*)(Bs_b + (rBoff[j] ^ kx));
        bl[j] = *(const f16x8*)(Bs_b + (rBoff[j] ^ kx ^ 64));
      }
#pragma unroll
      for (int i = 0; i < 4; ++i) {
        f16x8 ah = *(const f16x8*)(As_b + (rAoff[i] ^ kx));
        f16x8 al = *(const f16x8*)(As_b + (rAoff[i] ^ kx ^ 64));
#pragma unroll
        for (int j = 0; j < 4; ++j) {
          ahh[i][j] = __builtin_amdgcn_mfma_f32_16x16x32_f16(ah, bh[j], ahh[i][j], 0, 0, 0);
          axx[i][j] = __builtin_amdgcn_mfma_f32_16x16x32_f16(ah, bl[j], axx[i][j], 0, 0, 0);
          axx[i][j] = __builtin_amdgcn_mfma_f32_16x16x32_f16(al, bh[j], axx[i][j], 0, 0, 0);
        }
      }
    }
  }

  // epilogue: D row (A-side) = fq*4 + q (+16i), col (B-side) = fr (+16j)
#pragma unroll
  for (int i = 0; i < 4; ++i) {
#pragma unroll
    for (int q = 0; q < 4; ++q) {
      const int rg = tm0 + wm * 64 + i * 16 + fq * 4 + q;
      float s2 = 0.f;
#pragma unroll
      for (int j = 0; j < 4; ++j) {
        const int cg = tn0 + wn * 64 + j * 16 + fr;
        float val = ahh[i][j][q] + axx[i][j][q] * LOSCI;
        imp[(size_t)rg * DIM + cg] = val;
        _Float16 vh = (_Float16)val;
        _Float16 vl = (_Float16)((val - (float)vh) * LOSC);
        imph[(size_t)rg * DIM + cg] = vh;
        impl[(size_t)rg * DIM + cg] = vl;
        s2 += val * val;
      }
#pragma unroll
      for (int d = 1; d < 16; d <<= 1) s2 += __shfl_xor(s2, d, 64);
      if (fr == 0) atomicAdd(&c2[rg], s2);
    }
  }
}

// ---------------------------------------------------------------------------
// Kernel B (r8-validated core + T1 XCD swizzle): fused x @ implicit^T +
// per-row argmin, f16-split 3-pass MFMA, BK=64 single-buffer, XOR LDS.
// Block remap: XCD k owns by in [8k,8k+8) -> its 8 B-panels (2 MB) stay
// L2-hot, shortening the vmcnt(0) drain latency.  Bijective (4096 = 8*512).
// ---------------------------------------------------------------------------
__global__ __launch_bounds__(256, 2) void k_argmin(
    const _Float16* __restrict__ xh, const _Float16* __restrict__ xl,
    const _Float16* __restrict__ ch, const _Float16* __restrict__ cl,
    const float* __restrict__ c2, unsigned long long* __restrict__ best) {
  __shared__ _Float16 As[128 * 128];   // 32 KB (128 rows x 256 B)
  __shared__ _Float16 Bs[128 * 128];   // 32 KB
  const int t    = threadIdx.x;
  const int lane = t & 63, w = t >> 6;
  const int wm = w >> 1, wn = w & 1;
  const int fr = lane & 15, fq = lane >> 4;
  // XCD-aware bijective remap (4096 blocks = 8 XCDs x 512)
  const int flat = blockIdx.y * 64 + blockIdx.x;
  const int wg   = (flat & 7) * 512 + (flat >> 3);
  const int tm0 = (wg & 63) * 128;    // x rows
  const int tn0 = (wg >> 6) * 128;    // codebook entries

  f32x4 ahh[4][4], axx[4][4];
#pragma unroll
  for (int i = 0; i < 4; ++i)
#pragma unroll
    for (int j = 0; j < 4; ++j) {
      ahh[i][j] = (f32x4){0.f, 0.f, 0.f, 0.f};
      axx[i][j] = (f32x4){0.f, 0.f, 0.f, 0.f};
    }

  const int sBase = (lane & 15) ^ (lane >> 4);
  const int rIn   = lane >> 4;
  char* As_b = (char*)As;
  char* Bs_b = (char*)Bs;

  int rAoff[4], rBoff[4];
#pragma unroll
  for (int i = 0; i < 4; ++i) {
    rAoff[i] = (wm * 64 + i * 16 + fr) * 256 + ((fq ^ fr) << 4);
    rBoff[i] = (wn * 64 + i * 16 + fr) * 256 + ((fq ^ fr) << 4);
  }

  for (int kt = 0; kt < DIM; kt += BK) {
    __syncthreads();
#pragma unroll
    for (int q = 0; q < 8; ++q) {
      const int s    = sBase ^ ((q & 3) << 2);
      const int row  = w * 32 + q * 4 + rIn;
      const int koff = (s >> 3) * 32 + (s & 3) * 8;
      const _Float16* pa =
          ((s & 4) ? xl : xh) + (size_t)(tm0 + row) * DIM + kt + koff;
      const _Float16* pb =
          ((s & 4) ? cl : ch) + (size_t)(tn0 + row) * DIM + kt + koff;
      gload16(pa, As_b + (w * 32 + q * 4) * 256);
      gload16(pb, Bs_b + (w * 32 + q * 4) * 256);
    }
    __syncthreads();

#pragma unroll
    for (int kk = 0; kk < 2; ++kk) {
      const int kx = kk << 7;
      f16x8 bh[4], bl[4];
#pragma unroll
      for (int j = 0; j < 4; ++j) {
        bh[j] = *(const f16x8*)(Bs_b + (rBoff[j] ^ kx));
        bl[j] = *(const f16x8*)(Bs_b + (rBoff[j] ^ kx ^ 64));
      }
#pragma unroll
      for (int i = 0; i < 4; ++i) {
        f16x8 ah = *(const f16x8*)(As_b + (rAoff[i] ^ kx));
        f16x8 al = *(const f16x8*)(As_b + (rAoff[i] ^ kx ^ 64));
#pragma unroll
        for (int j = 0; j < 4; ++j) {
          ahh[i][j] = __builtin_amdgcn_mfma_f32_16x16x32_f16(ah, bh[j], ahh[i][j], 0, 0, 0);
          axx[i][j] = __builtin_amdgcn_mfma_f32_16x16x32_f16(ah, bl[j], axx[i][j], 0, 0, 0);
          axx[i][j] = __builtin_amdgcn_mfma_f32_16x16x32_f16(al, bh[j], axx[i][j], 0, 0, 0);
        }
      }
    }
  }

  // epilogue: D row = (lane>>4)*4 + reg, col = lane&15 (m89-verified mapping)
  float c2v[4];
  int   cgv[4];
#pragma unroll
  for (int j = 0; j < 4; ++j) {
    cgv[j] = tn0 + wn * 64 + j * 16 + fr;
    c2v[j] = c2[cgv[j]];
  }
  unsigned long long rmin[4][4];
#pragma unroll
  for (int i = 0; i < 4; ++i)
#pragma unroll
    for (int q = 0; q < 4; ++q) {
      unsigned long long m = ~0ull;
#pragma unroll
      for (int j = 0; j < 4; ++j) {
        float v = c2v[j] - 2.0f * (ahh[i][j][q] + axx[i][j][q] * LOSCI);
        unsigned long long p =
            ((unsigned long long)fkey(v) << 32) | (unsigned int)cgv[j];
        if (p < m) m = p;
      }
#pragma unroll
      for (int d = 1; d < 16; d <<= 1) {
        unsigned long long o = __shfl_xor(m, d, 64);
        if (o < m) m = o;
      }
      rmin[i][q] = m;
    }
  __syncthreads();
  unsigned long long* red = (unsigned long long*)As;   // 2 x 128 u64 = 2 KB
  if (fr == 0) {
#pragma unroll
    for (int i = 0; i < 4; ++i)
#pragma unroll
      for (int q = 0; q < 4; ++q)
        red[wn * 128 + wm * 64 + i * 16 + fq * 4 + q] = rmin[i][q];
  }
  __syncthreads();
  if (t < 128) {
    unsigned long long a = red[t], b = red[128 + t];
    if (b < a) a = b;
    atomicMin(&best[tm0 + t], a);
  }
}

// ---------------------------------------------------------------------------
// Kernel C (r8-validated): gather + STE + indices + commit loss.
// 16 rows per block, wave partials -> LDS -> ONE atomicAdd per block.
// ---------------------------------------------------------------------------
__global__ __launch_bounds__(256) void k_gather(
    const float* __restrict__ x, const float* __restrict__ imp,
    const unsigned long long* __restrict__ best,
    float* __restrict__ out_q, float* __restrict__ out_idx,
    float* __restrict__ out_loss) {
  __shared__ float part[4];
  const int wave = threadIdx.x >> 6;
  const int lane = threadIdx.x & 63;
  float s = 0.f;
#pragma unroll
  for (int rr = 0; rr < 4; ++rr) {
    const int r = blockIdx.x * 16 + wave * 4 + rr;
    const unsigned long long p = best[r];
    const int idx = (int)(p & 0xffffffffu);
    const float4* xr = (const float4*)(x   + (size_t)r   * DIM);
    const float4* qr = (const float4*)(imp + (size_t)idx * DIM);
    float4*       o  = (float4*)(out_q + (size_t)r * DIM);
#pragma unroll
    for (int jh = 0; jh < 2; ++jh) {
      float4 xv = xr[lane + jh * 64];
      float4 qv = qr[lane + jh * 64];
      float4 ov;
      ov.x = xv.x + (qv.x - xv.x);  ov.y = xv.y + (qv.y - xv.y);
      ov.z = xv.z + (qv.z - xv.z);  ov.w = xv.w + (qv.w - xv.w);
      o[lane + jh * 64] = ov;
      float dx = xv.x - qv.x, dy = xv.y - qv.y, dz = xv.z - qv.z, dw = xv.w - qv.w;
      s += dx*dx + dy*dy + dz*dz + dw*dw;
    }
    if (lane == 0) out_idx[r] = (float)idx;
  }
#pragma unroll
  for (int off = 32; off > 0; off >>= 1) s += __shfl_down(s, off);
  if (lane == 0) part[wave] = s;
  __syncthreads();
  if (threadIdx.x == 0) {
    float tot = (part[0] + part[1]) + (part[2] + part[3]);
    atomicAdd(out_loss, tot * (1.0f / (float)BN));
  }
}

// ---------------------------------------------------------------------------
extern "C" void kernel_launch(void* const* d_in, const int* in_sizes, int n_in,
                              void* d_out, int out_size, void* d_ws, size_t ws_size,
                              hipStream_t stream) {
  const float* x  = (const float*)d_in[0];  // [4,2048,512]
  const float* Wm = (const float*)d_in[1];  // [512,512]
  const float* cb = (const float*)d_in[2];  // [8192,512]

  float* out   = (float*)d_out;
  float* out_q = out;
  float* out_i = out + (size_t)BN * DIM;
  float* out_l = out + (size_t)BN * DIM + BN;

  char* ws = (char*)d_ws;
  float* imp = (float*)ws;                                            // 16 MiB
  float* c2  = (float*)(ws + 16777216);                               // 32 KiB
  unsigned long long* best = (unsigned long long*)(ws + 16809984);    // 64 KiB
  _Float16* xh  = (_Float16*)(ws + 16875520);                         // 8 MiB
  _Float16* xl  = (_Float16*)(ws + 16875520 + 1 * 8388608);
  _Float16* ih  = (_Float16*)(ws + 16875520 + 2 * 8388608);
  _Float16* il  = (_Float16*)(ws + 16875520 + 3 * 8388608);
  _Float16* cbh = (_Float16*)(ws + 16875520 + 4 * 8388608);
  _Float16* cbl = (_Float16*)(ws + 16875520 + 5 * 8388608);
  _Float16* Wh  = (_Float16*)(ws + 16875520 + 6 * 8388608);           // 512 KiB
  _Float16* Wl  = (_Float16*)(ws + 16875520 + 6 * 8388608 + 524288);  // 512 KiB

  k_prep<<<4256, 256, 0, stream>>>(x, xh, xl, cb, cbh, cbl, Wm, Wh, Wl,
                                   c2, best, out_l);

  dim3 gA(CBSZ / 128, DIM / 128);   // 64 x 4
  k_implicit<<<gA, 256, 0, stream>>>(cbh, cbl, Wh, Wl, imp, ih, il, c2);

  dim3 gB(BN / 128, CBSZ / 128);    // 64 x 64
  k_argmin<<<gB, 256, 0, stream>>>(xh, xl, ih, il, c2, best);

  k_gather<<<BN / 16, 256, 0, stream>>>(x, imp, best, out_q, out_i, out_l);
}